// Round 1
// baseline (1761.222 us; speedup 1.0000x reference)
//
#include <hip/hip_runtime.h>
#include <math.h>

#define DIM 128

// ---------------------------------------------------------------------------
// Graph build kernels
// ---------------------------------------------------------------------------

__global__ void count_k(const int* __restrict__ dst, int* __restrict__ counts, int E) {
    int e = blockIdx.x * 256 + threadIdx.x;
    if (e < E) atomicAdd(&counts[dst[e]], 1);
}

// per-block inclusive scan of counts -> incl, block sums -> bsum
__global__ void scan1_k(const int* __restrict__ counts, int* __restrict__ incl,
                        int* __restrict__ bsum, int n) {
    __shared__ int s[256];
    int i = blockIdx.x * 256 + threadIdx.x;
    int v = (i < n) ? counts[i] : 0;
    s[threadIdx.x] = v;
    __syncthreads();
    for (int off = 1; off < 256; off <<= 1) {
        int t = (threadIdx.x >= (unsigned)off) ? s[threadIdx.x - off] : 0;
        __syncthreads();
        s[threadIdx.x] += t;
        __syncthreads();
    }
    if (i < n) incl[i] = s[threadIdx.x];
    if (threadIdx.x == 255) bsum[blockIdx.x] = s[255];
}

// single-block scan of block sums (nb <= 512), in-place -> exclusive
__global__ void scan2_k(int* __restrict__ bsum, int nb) {
    __shared__ int s[512];
    int v = (threadIdx.x < (unsigned)nb) ? bsum[threadIdx.x] : 0;
    s[threadIdx.x] = v;
    __syncthreads();
    for (int off = 1; off < 512; off <<= 1) {
        int t = (threadIdx.x >= (unsigned)off) ? s[threadIdx.x - off] : 0;
        __syncthreads();
        s[threadIdx.x] += t;
        __syncthreads();
    }
    bsum[threadIdx.x] = s[threadIdx.x] - v;  // exclusive
}

// finalize: rowptr (exclusive), cursor copy, dis = rsqrt(deg) with deg = counts+1 (self loop)
__global__ void scan3_k(const int* __restrict__ counts, const int* __restrict__ incl,
                        const int* __restrict__ bsum, int* __restrict__ rowptr,
                        int* __restrict__ cursor, float* __restrict__ dis, int n, int E) {
    int i = blockIdx.x * 256 + threadIdx.x;
    if (i < n) {
        int excl = incl[i] - counts[i] + bsum[blockIdx.x];
        rowptr[i] = excl;
        cursor[i] = excl;
        dis[i]    = rsqrtf((float)(counts[i] + 1));
    }
    if (i == 0) rowptr[n] = E;
}

__global__ void fill_k(const int* __restrict__ src, const int* __restrict__ dst,
                       int* __restrict__ cursor, int* __restrict__ col,
                       float* __restrict__ wgt, const float* __restrict__ dis, int E) {
    int e = blockIdx.x * 256 + threadIdx.x;
    if (e < E) {
        int s = src[e], d = dst[e];
        int p = atomicAdd(&cursor[d], 1);
        col[p] = s;
        wgt[p] = dis[s] * dis[d];
    }
}

// ---------------------------------------------------------------------------
// GEMM: T[n,128] = A[n,128] @ W[128,128]   (fp32 vector ALU)
// grid: (ceil(n/256), 4) ; block 256 ; each thread: one row x 32 cols
// ---------------------------------------------------------------------------
__global__ __launch_bounds__(256) void gemm_k(const float* __restrict__ A,
                                              const float* __restrict__ W,
                                              float* __restrict__ T, int n) {
    const int row = blockIdx.x * 256 + threadIdx.x;
    const int c0  = blockIdx.y * 32;

    __shared__ float4 Wl[DIM][8];  // 128 k x 32 cols (8 float4) = 16 KB
    const float4* Wg = (const float4*)W;
    for (int i = threadIdx.x; i < DIM * 8; i += 256) {
        int k = i >> 3, j = i & 7;
        Wl[k][j] = Wg[k * 32 + (c0 >> 2) + j];
    }
    __syncthreads();

    if (row >= n) return;

    float acc[32];
#pragma unroll
    for (int c = 0; c < 32; ++c) acc[c] = 0.f;

    const float4* Arow = (const float4*)(A + (size_t)row * DIM);
    for (int kk = 0; kk < 32; ++kk) {
        float4 a4 = Arow[kk];
#pragma unroll
        for (int jj = 0; jj < 4; ++jj) {
            float a = (jj == 0) ? a4.x : (jj == 1) ? a4.y : (jj == 2) ? a4.z : a4.w;
            int k = kk * 4 + jj;
#pragma unroll
            for (int j = 0; j < 8; ++j) {
                float4 w4 = Wl[k][j];
                acc[j * 4 + 0] += a * w4.x;
                acc[j * 4 + 1] += a * w4.y;
                acc[j * 4 + 2] += a * w4.z;
                acc[j * 4 + 3] += a * w4.w;
            }
        }
    }

    float* Trow = T + (size_t)row * DIM + c0;
#pragma unroll
    for (int j = 0; j < 8; ++j) {
        float4 o;
        o.x = acc[j * 4 + 0]; o.y = acc[j * 4 + 1];
        o.z = acc[j * 4 + 2]; o.w = acc[j * 4 + 3];
        ((float4*)Trow)[j] = o;
    }
}

// ---------------------------------------------------------------------------
// Aggregation: O[v] = relu( dis[v]^2 * T[v] + sum_{e in CSR[v]} wgt[e]*T[col[e]] + b )
// one wave per node, lanes = 64 x float2 = 128 dims
// ---------------------------------------------------------------------------
__global__ __launch_bounds__(256) void agg_k(const float* __restrict__ T,
                                             const int* __restrict__ rowptr,
                                             const int* __restrict__ col,
                                             const float* __restrict__ wgt,
                                             const float* __restrict__ dis,
                                             const float* __restrict__ bias,
                                             float* __restrict__ O, int n) {
    int lane = threadIdx.x & 63;
    int v = blockIdx.x * 4 + (threadIdx.x >> 6);
    if (v >= n) return;

    const float2* T2 = (const float2*)T;
    float dv = dis[v];
    float2 t = T2[(size_t)v * 64 + lane];
    float2 acc;
    acc.x = t.x * dv * dv;
    acc.y = t.y * dv * dv;

    int e0 = rowptr[v], e1 = rowptr[v + 1];
    for (int e = e0; e < e1; ++e) {
        int c = col[e];
        float w = wgt[e];
        float2 u = T2[(size_t)c * 64 + lane];
        acc.x += w * u.x;
        acc.y += w * u.y;
    }

    float2 b = ((const float2*)bias)[lane];
    float2 o;
    o.x = fmaxf(acc.x + b.x, 0.f);
    o.y = fmaxf(acc.y + b.y, 0.f);
    ((float2*)O)[(size_t)v * 64 + lane] = o;
}

// ---------------------------------------------------------------------------
// Global mean pool: one block (64 threads) per graph; batch is sorted
// ---------------------------------------------------------------------------
__global__ __launch_bounds__(64) void pool_k(const float* __restrict__ H,
                                             const int* __restrict__ batch,
                                             float* __restrict__ G, int n) {
    int g = blockIdx.x;
    int lo = 0, hi = n;
    while (lo < hi) { int m = (lo + hi) >> 1; if (batch[m] < g) lo = m + 1; else hi = m; }
    int start = lo;
    lo = start; hi = n;
    while (lo < hi) { int m = (lo + hi) >> 1; if (batch[m] < g + 1) lo = m + 1; else hi = m; }
    int end = lo;

    int lane = threadIdx.x;
    const float2* H2 = (const float2*)H;
    float2 s = make_float2(0.f, 0.f);
    for (int v = start; v < end; ++v) {
        float2 h = H2[(size_t)v * 64 + lane];
        s.x += h.x; s.y += h.y;
    }
    float inv = 1.0f / fmaxf((float)(end - start), 1.0f);
    ((float2*)G)[g * 64 + lane] = make_float2(s.x * inv, s.y * inv);
}

// ---------------------------------------------------------------------------
// Head: y = relu(g@lin1+b1); logits = y@lin2+b2; out = log_softmax(logits)
// one block (128 threads) per graph
// ---------------------------------------------------------------------------
__global__ __launch_bounds__(128) void head_k(const float* __restrict__ G,
                                              const float* __restrict__ l1w,
                                              const float* __restrict__ l1b,
                                              const float* __restrict__ l2w,
                                              const float* __restrict__ l2b,
                                              float* __restrict__ out) {
    int g = blockIdx.x;
    int j = threadIdx.x;
    __shared__ float gs[128];
    __shared__ float2 red[128];

    gs[j] = G[g * 128 + j];
    __syncthreads();

    float acc = l1b[j];
    for (int k = 0; k < 128; ++k) acc += gs[k] * l1w[k * 128 + j];
    float y = fmaxf(acc, 0.f);

    red[j] = make_float2(y * l2w[j * 2 + 0], y * l2w[j * 2 + 1]);
    __syncthreads();
    for (int s = 64; s > 0; s >>= 1) {
        if (j < s) {
            red[j].x += red[j + s].x;
            red[j].y += red[j + s].y;
        }
        __syncthreads();
    }
    if (j == 0) {
        float l0 = red[0].x + l2b[0];
        float l1 = red[0].y + l2b[1];
        float m = fmaxf(l0, l1);
        float lse = m + logf(expf(l0 - m) + expf(l1 - m));
        out[g * 2 + 0] = l0 - lse;
        out[g * 2 + 1] = l1 - lse;
    }
}

// ---------------------------------------------------------------------------
// Launch
// ---------------------------------------------------------------------------
extern "C" void kernel_launch(void* const* d_in, const int* in_sizes, int n_in,
                              void* d_out, int out_size, void* d_ws, size_t ws_size,
                              hipStream_t stream) {
    const float* x       = (const float*)d_in[0];
    const int*   ei      = (const int*)d_in[1];
    const int*   batch   = (const int*)d_in[2];
    const float* conv_w  = (const float*)d_in[3];
    const float* conv_b  = (const float*)d_in[4];
    const float* lin1_w  = (const float*)d_in[5];
    const float* lin1_b  = (const float*)d_in[6];
    const float* lin2_w  = (const float*)d_in[7];
    const float* lin2_b  = (const float*)d_in[8];
    float* out = (float*)d_out;

    const int n = in_sizes[0] / DIM;      // 100000
    const int E = in_sizes[1] / 2;        // 1600000
    const int n_graphs = 128;

    const int* src = ei;
    const int* dst = ei + E;

    // workspace layout (all 256B aligned)
    char* p = (char*)d_ws;
    auto alloc = [&](size_t bytes) {
        char* r = p;
        p += (bytes + 255) & ~(size_t)255;
        return r;
    };
    float* bufA   = (float*)alloc((size_t)n * DIM * 4);
    float* bufB   = (float*)alloc((size_t)n * DIM * 4);
    float* dis    = (float*)alloc((size_t)n * 4);
    int*   counts = (int*)alloc((size_t)n * 4);
    int*   incl   = (int*)alloc((size_t)n * 4);
    int*   rowptr = (int*)alloc((size_t)(n + 1) * 4);
    int*   cursor = (int*)alloc((size_t)n * 4);
    int*   bsum   = (int*)alloc(512 * 4);
    int*   col    = (int*)alloc((size_t)E * 4);
    float* wgt    = (float*)alloc((size_t)E * 4);
    float* gbuf   = (float*)alloc((size_t)n_graphs * DIM * 4);
    (void)ws_size;

    const int nScanBlocks = (n + 255) / 256;        // 391 (<=512)
    const int eBlocks = (E + 255) / 256;

    hipMemsetAsync(counts, 0, (size_t)n * 4, stream);
    count_k<<<eBlocks, 256, 0, stream>>>(dst, counts, E);
    scan1_k<<<nScanBlocks, 256, 0, stream>>>(counts, incl, bsum, n);
    scan2_k<<<1, 512, 0, stream>>>(bsum, nScanBlocks);
    scan3_k<<<nScanBlocks, 256, 0, stream>>>(counts, incl, bsum, rowptr, cursor, dis, n, E);
    fill_k<<<eBlocks, 256, 0, stream>>>(src, dst, cursor, col, wgt, dis, E);

    dim3 ggrid((n + 255) / 256, 4);
    const int aggBlocks = (n + 3) / 4;

    // layer 0: x -> bufB -> bufA
    gemm_k<<<ggrid, 256, 0, stream>>>(x, conv_w + 0 * DIM * DIM, bufB, n);
    agg_k<<<aggBlocks, 256, 0, stream>>>(bufB, rowptr, col, wgt, dis, conv_b + 0 * DIM, bufA, n);
    // layer 1
    gemm_k<<<ggrid, 256, 0, stream>>>(bufA, conv_w + 1 * DIM * DIM, bufB, n);
    agg_k<<<aggBlocks, 256, 0, stream>>>(bufB, rowptr, col, wgt, dis, conv_b + 1 * DIM, bufA, n);
    // layer 2
    gemm_k<<<ggrid, 256, 0, stream>>>(bufA, conv_w + 2 * DIM * DIM, bufB, n);
    agg_k<<<aggBlocks, 256, 0, stream>>>(bufB, rowptr, col, wgt, dis, conv_b + 2 * DIM, bufA, n);

    pool_k<<<n_graphs, 64, 0, stream>>>(bufA, batch, gbuf, n);
    head_k<<<n_graphs, 128, 0, stream>>>(gbuf, lin1_w, lin1_b, lin2_w, lin2_b, out);
}

// Round 2
// 1161.218 us; speedup vs baseline: 1.5167x; 1.5167x over previous
//
#include <hip/hip_runtime.h>
#include <math.h>

#define DIM 128
#define GR 64          // rows per GEMM block
#define ALD 132        // A-tile LDS row stride (floats): %4==0 for b128, %32==4 -> conflict-free

// ---------------------------------------------------------------------------
// Graph build kernels
// ---------------------------------------------------------------------------

__global__ void count_k(const int* __restrict__ dst, int* __restrict__ counts, int E) {
    int e = blockIdx.x * 256 + threadIdx.x;
    if (e < E) atomicAdd(&counts[dst[e]], 1);
}

// per-block inclusive scan of counts -> incl, block sums -> bsum
__global__ void scan1_k(const int* __restrict__ counts, int* __restrict__ incl,
                        int* __restrict__ bsum, int n) {
    __shared__ int s[256];
    int i = blockIdx.x * 256 + threadIdx.x;
    int v = (i < n) ? counts[i] : 0;
    s[threadIdx.x] = v;
    __syncthreads();
    for (int off = 1; off < 256; off <<= 1) {
        int t = (threadIdx.x >= (unsigned)off) ? s[threadIdx.x - off] : 0;
        __syncthreads();
        s[threadIdx.x] += t;
        __syncthreads();
    }
    if (i < n) incl[i] = s[threadIdx.x];
    if (threadIdx.x == 255) bsum[blockIdx.x] = s[255];
}

// single-block scan of block sums (nb <= 512), in-place -> exclusive
__global__ void scan2_k(int* __restrict__ bsum, int nb) {
    __shared__ int s[512];
    int v = (threadIdx.x < (unsigned)nb) ? bsum[threadIdx.x] : 0;
    s[threadIdx.x] = v;
    __syncthreads();
    for (int off = 1; off < 512; off <<= 1) {
        int t = (threadIdx.x >= (unsigned)off) ? s[threadIdx.x - off] : 0;
        __syncthreads();
        s[threadIdx.x] += t;
        __syncthreads();
    }
    bsum[threadIdx.x] = s[threadIdx.x] - v;  // exclusive
}

// finalize: rowptr (exclusive), cursor copy, dis = rsqrt(deg) with deg = counts+1 (self loop)
__global__ void scan3_k(const int* __restrict__ counts, const int* __restrict__ incl,
                        const int* __restrict__ bsum, int* __restrict__ rowptr,
                        int* __restrict__ cursor, float* __restrict__ dis, int n, int E) {
    int i = blockIdx.x * 256 + threadIdx.x;
    if (i < n) {
        int excl = incl[i] - counts[i] + bsum[blockIdx.x];
        rowptr[i] = excl;
        cursor[i] = excl;
        dis[i]    = rsqrtf((float)(counts[i] + 1));
    }
    if (i == 0) rowptr[n] = E;
}

__global__ void fill_k(const int* __restrict__ src, const int* __restrict__ dst,
                       int* __restrict__ cursor, int* __restrict__ col,
                       float* __restrict__ wgt, const float* __restrict__ dis, int E) {
    int e = blockIdx.x * 256 + threadIdx.x;
    if (e < E) {
        int s = src[e], d = dst[e];
        int p = atomicAdd(&cursor[d], 1);
        col[p] = s;
        wgt[p] = dis[s] * dis[d];
    }
}

// ---------------------------------------------------------------------------
// GEMM: T[n,128] = A[n,128] @ W[128,128]   (fp32 vector ALU)
// block = 256 threads computes a 64x128 tile; A tile staged in LDS
// (coalesced), W streamed from L1/L2 (same 64 KB for every block).
// thread (ty=t>>5, tx=t&31): rows ty+8*i (i<8), cols 4*tx..4*tx+3.
// LDS bank check: A read lanes differ by ty -> addr delta 132 floats ->
// banks {0,4,...,28}; b128 spans 4 banks -> all 32 banks hit once. No conflict.
// ---------------------------------------------------------------------------
__global__ __launch_bounds__(256) void gemm_k(const float* __restrict__ A,
                                              const float* __restrict__ W,
                                              float* __restrict__ T, int n) {
    __shared__ float Al[GR * ALD];
    const int r0 = blockIdx.x * GR;
    const int t  = threadIdx.x;
    const int tx = t & 31;
    const int ty = t >> 5;

    const int nrows = min(GR, n - r0);
    // stage A tile: 64 rows x 32 float4, fully coalesced (wave = 2 rows of 1 KB)
    for (int idx = t; idx < GR * 32; idx += 256) {
        int row = idx >> 5, c4 = idx & 31;
        float4 v = make_float4(0.f, 0.f, 0.f, 0.f);
        if (row < nrows) v = ((const float4*)(A + (size_t)(r0 + row) * DIM))[c4];
        *(float4*)&Al[row * ALD + c4 * 4] = v;
    }
    __syncthreads();

    float acc[8][4];
#pragma unroll
    for (int i = 0; i < 8; ++i)
#pragma unroll
        for (int j = 0; j < 4; ++j) acc[i][j] = 0.f;

    const float4* Wg = (const float4*)W;
    for (int k = 0; k < DIM; k += 4) {
        float4 w0 = Wg[(k + 0) * 32 + tx];
        float4 w1 = Wg[(k + 1) * 32 + tx];
        float4 w2 = Wg[(k + 2) * 32 + tx];
        float4 w3 = Wg[(k + 3) * 32 + tx];
#pragma unroll
        for (int i = 0; i < 8; ++i) {
            const float4 a4 = *(const float4*)&Al[(ty + 8 * i) * ALD + k];
            acc[i][0] += a4.x * w0.x; acc[i][1] += a4.x * w0.y;
            acc[i][2] += a4.x * w0.z; acc[i][3] += a4.x * w0.w;
            acc[i][0] += a4.y * w1.x; acc[i][1] += a4.y * w1.y;
            acc[i][2] += a4.y * w1.z; acc[i][3] += a4.y * w1.w;
            acc[i][0] += a4.z * w2.x; acc[i][1] += a4.z * w2.y;
            acc[i][2] += a4.z * w2.z; acc[i][3] += a4.z * w2.w;
            acc[i][0] += a4.w * w3.x; acc[i][1] += a4.w * w3.y;
            acc[i][2] += a4.w * w3.z; acc[i][3] += a4.w * w3.w;
        }
    }

#pragma unroll
    for (int i = 0; i < 8; ++i) {
        int row = ty + 8 * i;
        if (row < nrows) {
            float4 o;
            o.x = acc[i][0]; o.y = acc[i][1]; o.z = acc[i][2]; o.w = acc[i][3];
            ((float4*)(T + (size_t)(r0 + row) * DIM))[tx] = o;
        }
    }
}

// ---------------------------------------------------------------------------
// Aggregation: O[v] = relu( dis[v]^2 * T[v] + sum_{e in CSR[v]} wgt[e]*T[col[e]] + b )
// one wave per node, lanes = 64 x float2 = 128 dims
// ---------------------------------------------------------------------------
__global__ __launch_bounds__(256) void agg_k(const float* __restrict__ T,
                                             const int* __restrict__ rowptr,
                                             const int* __restrict__ col,
                                             const float* __restrict__ wgt,
                                             const float* __restrict__ dis,
                                             const float* __restrict__ bias,
                                             float* __restrict__ O, int n) {
    int lane = threadIdx.x & 63;
    int v = blockIdx.x * 4 + (threadIdx.x >> 6);
    if (v >= n) return;

    const float2* T2 = (const float2*)T;
    float dv = dis[v];
    float2 t = T2[(size_t)v * 64 + lane];
    float2 acc;
    acc.x = t.x * dv * dv;
    acc.y = t.y * dv * dv;

    int e0 = rowptr[v], e1 = rowptr[v + 1];
    for (int e = e0; e < e1; ++e) {
        int c = col[e];
        float w = wgt[e];
        float2 u = T2[(size_t)c * 64 + lane];
        acc.x += w * u.x;
        acc.y += w * u.y;
    }

    float2 b = ((const float2*)bias)[lane];
    float2 o;
    o.x = fmaxf(acc.x + b.x, 0.f);
    o.y = fmaxf(acc.y + b.y, 0.f);
    ((float2*)O)[(size_t)v * 64 + lane] = o;
}

// ---------------------------------------------------------------------------
// Global mean pool: one block (64 threads) per graph; batch is sorted
// ---------------------------------------------------------------------------
__global__ __launch_bounds__(64) void pool_k(const float* __restrict__ H,
                                             const int* __restrict__ batch,
                                             float* __restrict__ G, int n) {
    int g = blockIdx.x;
    int lo = 0, hi = n;
    while (lo < hi) { int m = (lo + hi) >> 1; if (batch[m] < g) lo = m + 1; else hi = m; }
    int start = lo;
    lo = start; hi = n;
    while (lo < hi) { int m = (lo + hi) >> 1; if (batch[m] < g + 1) lo = m + 1; else hi = m; }
    int end = lo;

    int lane = threadIdx.x;
    const float2* H2 = (const float2*)H;
    float2 s = make_float2(0.f, 0.f);
    for (int v = start; v < end; ++v) {
        float2 h = H2[(size_t)v * 64 + lane];
        s.x += h.x; s.y += h.y;
    }
    float inv = 1.0f / fmaxf((float)(end - start), 1.0f);
    ((float2*)G)[g * 64 + lane] = make_float2(s.x * inv, s.y * inv);
}

// ---------------------------------------------------------------------------
// Head: y = relu(g@lin1+b1); logits = y@lin2+b2; out = log_softmax(logits)
// one block (128 threads) per graph
// ---------------------------------------------------------------------------
__global__ __launch_bounds__(128) void head_k(const float* __restrict__ G,
                                              const float* __restrict__ l1w,
                                              const float* __restrict__ l1b,
                                              const float* __restrict__ l2w,
                                              const float* __restrict__ l2b,
                                              float* __restrict__ out) {
    int g = blockIdx.x;
    int j = threadIdx.x;
    __shared__ float gs[128];
    __shared__ float2 red[128];

    gs[j] = G[g * 128 + j];
    __syncthreads();

    float acc = l1b[j];
    for (int k = 0; k < 128; ++k) acc += gs[k] * l1w[k * 128 + j];
    float y = fmaxf(acc, 0.f);

    red[j] = make_float2(y * l2w[j * 2 + 0], y * l2w[j * 2 + 1]);
    __syncthreads();
    for (int s = 64; s > 0; s >>= 1) {
        if (j < s) {
            red[j].x += red[j + s].x;
            red[j].y += red[j + s].y;
        }
        __syncthreads();
    }
    if (j == 0) {
        float l0 = red[0].x + l2b[0];
        float l1 = red[0].y + l2b[1];
        float m = fmaxf(l0, l1);
        float lse = m + logf(expf(l0 - m) + expf(l1 - m));
        out[g * 2 + 0] = l0 - lse;
        out[g * 2 + 1] = l1 - lse;
    }
}

// ---------------------------------------------------------------------------
// Launch
// ---------------------------------------------------------------------------
extern "C" void kernel_launch(void* const* d_in, const int* in_sizes, int n_in,
                              void* d_out, int out_size, void* d_ws, size_t ws_size,
                              hipStream_t stream) {
    const float* x       = (const float*)d_in[0];
    const int*   ei      = (const int*)d_in[1];
    const int*   batch   = (const int*)d_in[2];
    const float* conv_w  = (const float*)d_in[3];
    const float* conv_b  = (const float*)d_in[4];
    const float* lin1_w  = (const float*)d_in[5];
    const float* lin1_b  = (const float*)d_in[6];
    const float* lin2_w  = (const float*)d_in[7];
    const float* lin2_b  = (const float*)d_in[8];
    float* out = (float*)d_out;

    const int n = in_sizes[0] / DIM;      // 100000
    const int E = in_sizes[1] / 2;        // 1600000
    const int n_graphs = 128;

    const int* src = ei;
    const int* dst = ei + E;

    // workspace layout (all 256B aligned)
    char* p = (char*)d_ws;
    auto alloc = [&](size_t bytes) {
        char* r = p;
        p += (bytes + 255) & ~(size_t)255;
        return r;
    };
    float* bufA   = (float*)alloc((size_t)n * DIM * 4);
    float* bufB   = (float*)alloc((size_t)n * DIM * 4);
    float* dis    = (float*)alloc((size_t)n * 4);
    int*   counts = (int*)alloc((size_t)n * 4);
    int*   incl   = (int*)alloc((size_t)n * 4);
    int*   rowptr = (int*)alloc((size_t)(n + 1) * 4);
    int*   cursor = (int*)alloc((size_t)n * 4);
    int*   bsum   = (int*)alloc(512 * 4);
    int*   col    = (int*)alloc((size_t)E * 4);
    float* wgt    = (float*)alloc((size_t)E * 4);
    float* gbuf   = (float*)alloc((size_t)n_graphs * DIM * 4);
    (void)ws_size;

    const int nScanBlocks = (n + 255) / 256;        // 391 (<=512)
    const int eBlocks = (E + 255) / 256;

    hipMemsetAsync(counts, 0, (size_t)n * 4, stream);
    count_k<<<eBlocks, 256, 0, stream>>>(dst, counts, E);
    scan1_k<<<nScanBlocks, 256, 0, stream>>>(counts, incl, bsum, n);
    scan2_k<<<1, 512, 0, stream>>>(bsum, nScanBlocks);
    scan3_k<<<nScanBlocks, 256, 0, stream>>>(counts, incl, bsum, rowptr, cursor, dis, n, E);
    fill_k<<<eBlocks, 256, 0, stream>>>(src, dst, cursor, col, wgt, dis, E);

    const int gemmBlocks = (n + GR - 1) / GR;
    const int aggBlocks = (n + 3) / 4;

    // layer 0: x -> bufB -> bufA
    gemm_k<<<gemmBlocks, 256, 0, stream>>>(x, conv_w + 0 * DIM * DIM, bufB, n);
    agg_k<<<aggBlocks, 256, 0, stream>>>(bufB, rowptr, col, wgt, dis, conv_b + 0 * DIM, bufA, n);
    // layer 1
    gemm_k<<<gemmBlocks, 256, 0, stream>>>(bufA, conv_w + 1 * DIM * DIM, bufB, n);
    agg_k<<<aggBlocks, 256, 0, stream>>>(bufB, rowptr, col, wgt, dis, conv_b + 1 * DIM, bufA, n);
    // layer 2
    gemm_k<<<gemmBlocks, 256, 0, stream>>>(bufA, conv_w + 2 * DIM * DIM, bufB, n);
    agg_k<<<aggBlocks, 256, 0, stream>>>(bufB, rowptr, col, wgt, dis, conv_b + 2 * DIM, bufA, n);

    pool_k<<<n_graphs, 64, 0, stream>>>(bufA, batch, gbuf, n);
    head_k<<<n_graphs, 128, 0, stream>>>(gbuf, lin1_w, lin1_b, lin2_w, lin2_b, out);
}

// Round 3
// 972.100 us; speedup vs baseline: 1.8118x; 1.1945x over previous
//
#include <hip/hip_runtime.h>
#include <math.h>

#define DIM 128
#define GR 64          // rows per GEMM block
#define ALD 132        // A-tile LDS row stride (floats): %4==0 for b128, %32==4 -> conflict-free
#define POOL_SPLIT 32  // partial-sum blocks per graph

// ---------------------------------------------------------------------------
// Graph build kernels
// ---------------------------------------------------------------------------

__global__ void count_k(const int* __restrict__ dst, int* __restrict__ counts, int E) {
    int e = blockIdx.x * 256 + threadIdx.x;
    if (e < E) atomicAdd(&counts[dst[e]], 1);
}

// per-block inclusive scan of counts -> incl, block sums -> bsum
__global__ void scan1_k(const int* __restrict__ counts, int* __restrict__ incl,
                        int* __restrict__ bsum, int n) {
    __shared__ int s[256];
    int i = blockIdx.x * 256 + threadIdx.x;
    int v = (i < n) ? counts[i] : 0;
    s[threadIdx.x] = v;
    __syncthreads();
    for (int off = 1; off < 256; off <<= 1) {
        int t = (threadIdx.x >= (unsigned)off) ? s[threadIdx.x - off] : 0;
        __syncthreads();
        s[threadIdx.x] += t;
        __syncthreads();
    }
    if (i < n) incl[i] = s[threadIdx.x];
    if (threadIdx.x == 255) bsum[blockIdx.x] = s[255];
}

// single-block scan of block sums (nb <= 512), in-place -> exclusive
__global__ void scan2_k(int* __restrict__ bsum, int nb) {
    __shared__ int s[512];
    int v = (threadIdx.x < (unsigned)nb) ? bsum[threadIdx.x] : 0;
    s[threadIdx.x] = v;
    __syncthreads();
    for (int off = 1; off < 512; off <<= 1) {
        int t = (threadIdx.x >= (unsigned)off) ? s[threadIdx.x - off] : 0;
        __syncthreads();
        s[threadIdx.x] += t;
        __syncthreads();
    }
    bsum[threadIdx.x] = s[threadIdx.x] - v;  // exclusive
}

// finalize: rowptr (exclusive), cursor copy, dis = rsqrt(deg) with deg = counts+1 (self loop)
__global__ void scan3_k(const int* __restrict__ counts, const int* __restrict__ incl,
                        const int* __restrict__ bsum, int* __restrict__ rowptr,
                        int* __restrict__ cursor, float* __restrict__ dis, int n, int E) {
    int i = blockIdx.x * 256 + threadIdx.x;
    if (i < n) {
        int excl = incl[i] - counts[i] + bsum[blockIdx.x];
        rowptr[i] = excl;
        cursor[i] = excl;
        dis[i]    = rsqrtf((float)(counts[i] + 1));
    }
    if (i == 0) rowptr[n] = E;
}

__global__ void fill_k(const int* __restrict__ src, const int* __restrict__ dst,
                       int* __restrict__ cursor, int* __restrict__ col,
                       float* __restrict__ wgt, const float* __restrict__ dis, int E) {
    int e = blockIdx.x * 256 + threadIdx.x;
    if (e < E) {
        int s = src[e], d = dst[e];
        int p = atomicAdd(&cursor[d], 1);
        col[p] = s;
        wgt[p] = dis[s] * dis[d];
    }
}

// ---------------------------------------------------------------------------
// GEMM: T[n,128] = A[n,128] @ W[128,128]   (fp32 vector ALU)
// block = 256 threads computes a 64x128 tile; A tile staged in LDS
// (coalesced), W streamed from L1/L2 (same 64 KB for every block).
// ---------------------------------------------------------------------------
__global__ __launch_bounds__(256) void gemm_k(const float* __restrict__ A,
                                              const float* __restrict__ W,
                                              float* __restrict__ T, int n) {
    __shared__ float Al[GR * ALD];
    const int r0 = blockIdx.x * GR;
    const int t  = threadIdx.x;
    const int tx = t & 31;
    const int ty = t >> 5;

    const int nrows = min(GR, n - r0);
    for (int idx = t; idx < GR * 32; idx += 256) {
        int row = idx >> 5, c4 = idx & 31;
        float4 v = make_float4(0.f, 0.f, 0.f, 0.f);
        if (row < nrows) v = ((const float4*)(A + (size_t)(r0 + row) * DIM))[c4];
        *(float4*)&Al[row * ALD + c4 * 4] = v;
    }
    __syncthreads();

    float acc[8][4];
#pragma unroll
    for (int i = 0; i < 8; ++i)
#pragma unroll
        for (int j = 0; j < 4; ++j) acc[i][j] = 0.f;

    const float4* Wg = (const float4*)W;
    for (int k = 0; k < DIM; k += 4) {
        float4 w0 = Wg[(k + 0) * 32 + tx];
        float4 w1 = Wg[(k + 1) * 32 + tx];
        float4 w2 = Wg[(k + 2) * 32 + tx];
        float4 w3 = Wg[(k + 3) * 32 + tx];
#pragma unroll
        for (int i = 0; i < 8; ++i) {
            const float4 a4 = *(const float4*)&Al[(ty + 8 * i) * ALD + k];
            acc[i][0] += a4.x * w0.x; acc[i][1] += a4.x * w0.y;
            acc[i][2] += a4.x * w0.z; acc[i][3] += a4.x * w0.w;
            acc[i][0] += a4.y * w1.x; acc[i][1] += a4.y * w1.y;
            acc[i][2] += a4.y * w1.z; acc[i][3] += a4.y * w1.w;
            acc[i][0] += a4.z * w2.x; acc[i][1] += a4.z * w2.y;
            acc[i][2] += a4.z * w2.z; acc[i][3] += a4.z * w2.w;
            acc[i][0] += a4.w * w3.x; acc[i][1] += a4.w * w3.y;
            acc[i][2] += a4.w * w3.z; acc[i][3] += a4.w * w3.w;
        }
    }

#pragma unroll
    for (int i = 0; i < 8; ++i) {
        int row = ty + 8 * i;
        if (row < nrows) {
            float4 o;
            o.x = acc[i][0]; o.y = acc[i][1]; o.z = acc[i][2]; o.w = acc[i][3];
            ((float4*)(T + (size_t)(r0 + row) * DIM))[tx] = o;
        }
    }
}

// ---------------------------------------------------------------------------
// Aggregation: O[v] = relu( dis[v]^2 * T[v] + sum_{e in CSR[v]} wgt[e]*T[col[e]] + b )
// one wave per node, lanes = 64 x float2 = 128 dims
// ---------------------------------------------------------------------------
__global__ __launch_bounds__(256) void agg_k(const float* __restrict__ T,
                                             const int* __restrict__ rowptr,
                                             const int* __restrict__ col,
                                             const float* __restrict__ wgt,
                                             const float* __restrict__ dis,
                                             const float* __restrict__ bias,
                                             float* __restrict__ O, int n) {
    int lane = threadIdx.x & 63;
    int v = blockIdx.x * 4 + (threadIdx.x >> 6);
    if (v >= n) return;

    const float2* T2 = (const float2*)T;
    float dv = dis[v];
    float2 t = T2[(size_t)v * 64 + lane];
    float2 acc;
    acc.x = t.x * dv * dv;
    acc.y = t.y * dv * dv;

    int e0 = rowptr[v], e1 = rowptr[v + 1];
    for (int e = e0; e < e1; ++e) {
        int c = col[e];
        float w = wgt[e];
        float2 u = T2[(size_t)c * 64 + lane];
        acc.x += w * u.x;
        acc.y += w * u.y;
    }

    float2 b = ((const float2*)bias)[lane];
    float2 o;
    o.x = fmaxf(acc.x + b.x, 0.f);
    o.y = fmaxf(acc.y + b.y, 0.f);
    ((float2*)O)[(size_t)v * 64 + lane] = o;
}

// ---------------------------------------------------------------------------
// Global mean pool, split-parallel: grid (n_graphs, POOL_SPLIT), block = 1 wave.
// Each block sums rows start+part, start+part+32, ... of its graph, pre-scales
// by 1/cnt, atomically accumulates into G (zeroed before launch).
// ---------------------------------------------------------------------------
__global__ __launch_bounds__(64) void pool_k(const float* __restrict__ H,
                                             const int* __restrict__ batch,
                                             float* __restrict__ G, int n) {
    int g = blockIdx.x;
    int part = blockIdx.y;

    int lo = 0, hi = n;
    while (lo < hi) { int m = (lo + hi) >> 1; if (batch[m] < g) lo = m + 1; else hi = m; }
    int start = lo;
    lo = start; hi = n;
    while (lo < hi) { int m = (lo + hi) >> 1; if (batch[m] < g + 1) lo = m + 1; else hi = m; }
    int end = lo;
    int cnt = end - start;
    if (cnt <= 0) return;
    float inv = 1.0f / (float)cnt;

    int lane = threadIdx.x;
    const float2* H2 = (const float2*)H;
    float2 s = make_float2(0.f, 0.f);
    for (int v = start + part; v < end; v += POOL_SPLIT) {
        float2 h = H2[(size_t)v * 64 + lane];
        s.x += h.x; s.y += h.y;
    }
    atomicAdd(&G[g * DIM + 2 * lane + 0], s.x * inv);
    atomicAdd(&G[g * DIM + 2 * lane + 1], s.y * inv);
}

// ---------------------------------------------------------------------------
// Head: y = relu(g@lin1+b1); logits = y@lin2+b2; out = log_softmax(logits)
// one block (128 threads) per graph
// ---------------------------------------------------------------------------
__global__ __launch_bounds__(128) void head_k(const float* __restrict__ G,
                                              const float* __restrict__ l1w,
                                              const float* __restrict__ l1b,
                                              const float* __restrict__ l2w,
                                              const float* __restrict__ l2b,
                                              float* __restrict__ out) {
    int g = blockIdx.x;
    int j = threadIdx.x;
    __shared__ float gs[128];
    __shared__ float2 red[128];

    gs[j] = G[g * 128 + j];
    __syncthreads();

    float acc = l1b[j];
    for (int k = 0; k < 128; ++k) acc += gs[k] * l1w[k * 128 + j];
    float y = fmaxf(acc, 0.f);

    red[j] = make_float2(y * l2w[j * 2 + 0], y * l2w[j * 2 + 1]);
    __syncthreads();
    for (int s = 64; s > 0; s >>= 1) {
        if (j < s) {
            red[j].x += red[j + s].x;
            red[j].y += red[j + s].y;
        }
        __syncthreads();
    }
    if (j == 0) {
        float l0 = red[0].x + l2b[0];
        float l1 = red[0].y + l2b[1];
        float m = fmaxf(l0, l1);
        float lse = m + logf(expf(l0 - m) + expf(l1 - m));
        out[g * 2 + 0] = l0 - lse;
        out[g * 2 + 1] = l1 - lse;
    }
}

// ---------------------------------------------------------------------------
// Launch
// ---------------------------------------------------------------------------
extern "C" void kernel_launch(void* const* d_in, const int* in_sizes, int n_in,
                              void* d_out, int out_size, void* d_ws, size_t ws_size,
                              hipStream_t stream) {
    const float* x       = (const float*)d_in[0];
    const int*   ei      = (const int*)d_in[1];
    const int*   batch   = (const int*)d_in[2];
    const float* conv_w  = (const float*)d_in[3];
    const float* conv_b  = (const float*)d_in[4];
    const float* lin1_w  = (const float*)d_in[5];
    const float* lin1_b  = (const float*)d_in[6];
    const float* lin2_w  = (const float*)d_in[7];
    const float* lin2_b  = (const float*)d_in[8];
    float* out = (float*)d_out;

    const int n = in_sizes[0] / DIM;      // 100000
    const int E = in_sizes[1] / 2;        // 1600000
    const int n_graphs = 128;

    const int* src = ei;
    const int* dst = ei + E;

    // workspace layout (all 256B aligned)
    char* p = (char*)d_ws;
    auto alloc = [&](size_t bytes) {
        char* r = p;
        p += (bytes + 255) & ~(size_t)255;
        return r;
    };
    float* bufA   = (float*)alloc((size_t)n * DIM * 4);
    float* bufB   = (float*)alloc((size_t)n * DIM * 4);
    float* dis    = (float*)alloc((size_t)n * 4);
    int*   counts = (int*)alloc((size_t)n * 4);
    int*   incl   = (int*)alloc((size_t)n * 4);
    int*   rowptr = (int*)alloc((size_t)(n + 1) * 4);
    int*   cursor = (int*)alloc((size_t)n * 4);
    int*   bsum   = (int*)alloc(512 * 4);
    int*   col    = (int*)alloc((size_t)E * 4);
    float* wgt    = (float*)alloc((size_t)E * 4);
    float* gbuf   = (float*)alloc((size_t)n_graphs * DIM * 4);
    (void)ws_size;

    const int nScanBlocks = (n + 255) / 256;        // 391 (<=512)
    const int eBlocks = (E + 255) / 256;

    hipMemsetAsync(counts, 0, (size_t)n * 4, stream);
    hipMemsetAsync(gbuf, 0, (size_t)n_graphs * DIM * 4, stream);
    count_k<<<eBlocks, 256, 0, stream>>>(dst, counts, E);
    scan1_k<<<nScanBlocks, 256, 0, stream>>>(counts, incl, bsum, n);
    scan2_k<<<1, 512, 0, stream>>>(bsum, nScanBlocks);
    scan3_k<<<nScanBlocks, 256, 0, stream>>>(counts, incl, bsum, rowptr, cursor, dis, n, E);
    fill_k<<<eBlocks, 256, 0, stream>>>(src, dst, cursor, col, wgt, dis, E);

    const int gemmBlocks = (n + GR - 1) / GR;
    const int aggBlocks = (n + 3) / 4;

    // layer 0: x -> bufB -> bufA
    gemm_k<<<gemmBlocks, 256, 0, stream>>>(x, conv_w + 0 * DIM * DIM, bufB, n);
    agg_k<<<aggBlocks, 256, 0, stream>>>(bufB, rowptr, col, wgt, dis, conv_b + 0 * DIM, bufA, n);
    // layer 1
    gemm_k<<<gemmBlocks, 256, 0, stream>>>(bufA, conv_w + 1 * DIM * DIM, bufB, n);
    agg_k<<<aggBlocks, 256, 0, stream>>>(bufB, rowptr, col, wgt, dis, conv_b + 1 * DIM, bufA, n);
    // layer 2
    gemm_k<<<gemmBlocks, 256, 0, stream>>>(bufA, conv_w + 2 * DIM * DIM, bufB, n);
    agg_k<<<aggBlocks, 256, 0, stream>>>(bufB, rowptr, col, wgt, dis, conv_b + 2 * DIM, bufA, n);

    dim3 pgrid(n_graphs, POOL_SPLIT);
    pool_k<<<pgrid, 64, 0, stream>>>(bufA, batch, gbuf, n);
    head_k<<<n_graphs, 128, 0, stream>>>(gbuf, lin1_w, lin1_b, lin2_w, lin2_b, out);
}

// Round 4
// 809.031 us; speedup vs baseline: 2.1770x; 1.2016x over previous
//
#include <hip/hip_runtime.h>
#include <math.h>

#define DIM 128
#define GR 64          // rows per GEMM block
#define ALD 132        // A-tile LDS row stride (floats): %4==0 for b128, %32==4 -> conflict-free
#define POOL_SPLIT 32  // partial-sum blocks per graph

// ---------------------------------------------------------------------------
// Graph build kernels
// ---------------------------------------------------------------------------

__global__ void count_k(const int* __restrict__ dst, int* __restrict__ counts, int E) {
    int e = blockIdx.x * 256 + threadIdx.x;
    if (e < E) atomicAdd(&counts[dst[e]], 1);
}

// per-block inclusive scan of counts -> incl, block sums -> bsum
__global__ void scan1_k(const int* __restrict__ counts, int* __restrict__ incl,
                        int* __restrict__ bsum, int n) {
    __shared__ int s[256];
    int i = blockIdx.x * 256 + threadIdx.x;
    int v = (i < n) ? counts[i] : 0;
    s[threadIdx.x] = v;
    __syncthreads();
    for (int off = 1; off < 256; off <<= 1) {
        int t = (threadIdx.x >= (unsigned)off) ? s[threadIdx.x - off] : 0;
        __syncthreads();
        s[threadIdx.x] += t;
        __syncthreads();
    }
    if (i < n) incl[i] = s[threadIdx.x];
    if (threadIdx.x == 255) bsum[blockIdx.x] = s[255];
}

// single-block scan of block sums (nb <= 512), in-place -> exclusive
__global__ void scan2_k(int* __restrict__ bsum, int nb) {
    __shared__ int s[512];
    int v = (threadIdx.x < (unsigned)nb) ? bsum[threadIdx.x] : 0;
    s[threadIdx.x] = v;
    __syncthreads();
    for (int off = 1; off < 512; off <<= 1) {
        int t = (threadIdx.x >= (unsigned)off) ? s[threadIdx.x - off] : 0;
        __syncthreads();
        s[threadIdx.x] += t;
        __syncthreads();
    }
    bsum[threadIdx.x] = s[threadIdx.x] - v;  // exclusive
}

// finalize: rowptr (exclusive), cursor copy, dis = rsqrt(deg) with deg = counts+1 (self loop)
__global__ void scan3_k(const int* __restrict__ counts, const int* __restrict__ incl,
                        const int* __restrict__ bsum, int* __restrict__ rowptr,
                        int* __restrict__ cursor, float* __restrict__ dis, int n, int E) {
    int i = blockIdx.x * 256 + threadIdx.x;
    if (i < n) {
        int excl = incl[i] - counts[i] + bsum[blockIdx.x];
        rowptr[i] = excl;
        cursor[i] = excl;
        dis[i]    = rsqrtf((float)(counts[i] + 1));
    }
    if (i == 0) rowptr[n] = E;
}

__global__ void fill_k(const int* __restrict__ src, const int* __restrict__ dst,
                       int* __restrict__ cursor, int* __restrict__ col,
                       float* __restrict__ wgt, const float* __restrict__ dis, int E) {
    int e = blockIdx.x * 256 + threadIdx.x;
    if (e < E) {
        int s = src[e], d = dst[e];
        int p = atomicAdd(&cursor[d], 1);
        col[p] = s;
        wgt[p] = dis[s] * dis[d];
    }
}

// ---------------------------------------------------------------------------
// GEMM: T[n,128] = A[n,128] @ W[128,128]   (fp32 vector ALU)
// block = 256 threads computes a 64x128 tile; A tile staged in LDS
// (coalesced), W streamed from L1/L2 (same 64 KB for every block).
// ---------------------------------------------------------------------------
__global__ __launch_bounds__(256) void gemm_k(const float* __restrict__ A,
                                              const float* __restrict__ W,
                                              float* __restrict__ T, int n) {
    __shared__ float Al[GR * ALD];
    const int r0 = blockIdx.x * GR;
    const int t  = threadIdx.x;
    const int tx = t & 31;
    const int ty = t >> 5;

    const int nrows = min(GR, n - r0);
    for (int idx = t; idx < GR * 32; idx += 256) {
        int row = idx >> 5, c4 = idx & 31;
        float4 v = make_float4(0.f, 0.f, 0.f, 0.f);
        if (row < nrows) v = ((const float4*)(A + (size_t)(r0 + row) * DIM))[c4];
        *(float4*)&Al[row * ALD + c4 * 4] = v;
    }
    __syncthreads();

    float acc[8][4];
#pragma unroll
    for (int i = 0; i < 8; ++i)
#pragma unroll
        for (int j = 0; j < 4; ++j) acc[i][j] = 0.f;

    const float4* Wg = (const float4*)W;
    for (int k = 0; k < DIM; k += 4) {
        float4 w0 = Wg[(k + 0) * 32 + tx];
        float4 w1 = Wg[(k + 1) * 32 + tx];
        float4 w2 = Wg[(k + 2) * 32 + tx];
        float4 w3 = Wg[(k + 3) * 32 + tx];
#pragma unroll
        for (int i = 0; i < 8; ++i) {
            const float4 a4 = *(const float4*)&Al[(ty + 8 * i) * ALD + k];
            acc[i][0] += a4.x * w0.x; acc[i][1] += a4.x * w0.y;
            acc[i][2] += a4.x * w0.z; acc[i][3] += a4.x * w0.w;
            acc[i][0] += a4.y * w1.x; acc[i][1] += a4.y * w1.y;
            acc[i][2] += a4.y * w1.z; acc[i][3] += a4.y * w1.w;
            acc[i][0] += a4.z * w2.x; acc[i][1] += a4.z * w2.y;
            acc[i][2] += a4.z * w2.z; acc[i][3] += a4.z * w2.w;
            acc[i][0] += a4.w * w3.x; acc[i][1] += a4.w * w3.y;
            acc[i][2] += a4.w * w3.z; acc[i][3] += a4.w * w3.w;
        }
    }

#pragma unroll
    for (int i = 0; i < 8; ++i) {
        int row = ty + 8 * i;
        if (row < nrows) {
            float4 o;
            o.x = acc[i][0]; o.y = acc[i][1]; o.z = acc[i][2]; o.w = acc[i][3];
            ((float4*)(T + (size_t)(r0 + row) * DIM))[tx] = o;
        }
    }
}

// ---------------------------------------------------------------------------
// Aggregation: O[v] = relu( dis[v]^2 * T[v] + sum_{e in CSR[v]} wgt[e]*T[col[e]] + b )
// one wave per node, lanes = 64 x float2 = 128 dims.
// Edge loop unrolled 8/4 to keep multiple independent row-gathers in flight
// (MLP): VGPR=12 in the rolled version serialized one ~600ns gather at a time.
// ---------------------------------------------------------------------------
__global__ __launch_bounds__(256) void agg_k(const float* __restrict__ T,
                                             const int* __restrict__ rowptr,
                                             const int* __restrict__ col,
                                             const float* __restrict__ wgt,
                                             const float* __restrict__ dis,
                                             const float* __restrict__ bias,
                                             float* __restrict__ O, int n) {
    int lane = threadIdx.x & 63;
    int v = blockIdx.x * 4 + (threadIdx.x >> 6);
    if (v >= n) return;

    const float2* T2 = (const float2*)T;
    float dv = dis[v];
    int e0 = rowptr[v], e1 = rowptr[v + 1];

    float2 t = T2[(size_t)v * 64 + lane];
    float2 acc;
    acc.x = t.x * dv * dv;
    acc.y = t.y * dv * dv;

    int e = e0;
    for (; e + 8 <= e1; e += 8) {
        int   c0 = col[e + 0], c1 = col[e + 1], c2 = col[e + 2], c3 = col[e + 3];
        int   c4 = col[e + 4], c5 = col[e + 5], c6 = col[e + 6], c7 = col[e + 7];
        float w0 = wgt[e + 0], w1 = wgt[e + 1], w2 = wgt[e + 2], w3 = wgt[e + 3];
        float w4 = wgt[e + 4], w5 = wgt[e + 5], w6 = wgt[e + 6], w7 = wgt[e + 7];
        float2 u0 = T2[(size_t)c0 * 64 + lane];
        float2 u1 = T2[(size_t)c1 * 64 + lane];
        float2 u2 = T2[(size_t)c2 * 64 + lane];
        float2 u3 = T2[(size_t)c3 * 64 + lane];
        float2 u4 = T2[(size_t)c4 * 64 + lane];
        float2 u5 = T2[(size_t)c5 * 64 + lane];
        float2 u6 = T2[(size_t)c6 * 64 + lane];
        float2 u7 = T2[(size_t)c7 * 64 + lane];
        acc.x += w0 * u0.x; acc.y += w0 * u0.y;
        acc.x += w1 * u1.x; acc.y += w1 * u1.y;
        acc.x += w2 * u2.x; acc.y += w2 * u2.y;
        acc.x += w3 * u3.x; acc.y += w3 * u3.y;
        acc.x += w4 * u4.x; acc.y += w4 * u4.y;
        acc.x += w5 * u5.x; acc.y += w5 * u5.y;
        acc.x += w6 * u6.x; acc.y += w6 * u6.y;
        acc.x += w7 * u7.x; acc.y += w7 * u7.y;
    }
    for (; e + 4 <= e1; e += 4) {
        int   c0 = col[e + 0], c1 = col[e + 1], c2 = col[e + 2], c3 = col[e + 3];
        float w0 = wgt[e + 0], w1 = wgt[e + 1], w2 = wgt[e + 2], w3 = wgt[e + 3];
        float2 u0 = T2[(size_t)c0 * 64 + lane];
        float2 u1 = T2[(size_t)c1 * 64 + lane];
        float2 u2 = T2[(size_t)c2 * 64 + lane];
        float2 u3 = T2[(size_t)c3 * 64 + lane];
        acc.x += w0 * u0.x; acc.y += w0 * u0.y;
        acc.x += w1 * u1.x; acc.y += w1 * u1.y;
        acc.x += w2 * u2.x; acc.y += w2 * u2.y;
        acc.x += w3 * u3.x; acc.y += w3 * u3.y;
    }
    for (; e < e1; ++e) {
        int c = col[e];
        float w = wgt[e];
        float2 u = T2[(size_t)c * 64 + lane];
        acc.x += w * u.x;
        acc.y += w * u.y;
    }

    float2 b = ((const float2*)bias)[lane];
    float2 o;
    o.x = fmaxf(acc.x + b.x, 0.f);
    o.y = fmaxf(acc.y + b.y, 0.f);
    ((float2*)O)[(size_t)v * 64 + lane] = o;
}

// ---------------------------------------------------------------------------
// Global mean pool, split-parallel: grid (n_graphs, POOL_SPLIT), block = 1 wave.
// ---------------------------------------------------------------------------
__global__ __launch_bounds__(64) void pool_k(const float* __restrict__ H,
                                             const int* __restrict__ batch,
                                             float* __restrict__ G, int n) {
    int g = blockIdx.x;
    int part = blockIdx.y;

    int lo = 0, hi = n;
    while (lo < hi) { int m = (lo + hi) >> 1; if (batch[m] < g) lo = m + 1; else hi = m; }
    int start = lo;
    lo = start; hi = n;
    while (lo < hi) { int m = (lo + hi) >> 1; if (batch[m] < g + 1) lo = m + 1; else hi = m; }
    int end = lo;
    int cnt = end - start;
    if (cnt <= 0) return;
    float inv = 1.0f / (float)cnt;

    int lane = threadIdx.x;
    const float2* H2 = (const float2*)H;
    float2 s = make_float2(0.f, 0.f);
    for (int v = start + part; v < end; v += POOL_SPLIT) {
        float2 h = H2[(size_t)v * 64 + lane];
        s.x += h.x; s.y += h.y;
    }
    atomicAdd(&G[g * DIM + 2 * lane + 0], s.x * inv);
    atomicAdd(&G[g * DIM + 2 * lane + 1], s.y * inv);
}

// ---------------------------------------------------------------------------
// Head: y = relu(g@lin1+b1); logits = y@lin2+b2; out = log_softmax(logits)
// one block (128 threads) per graph
// ---------------------------------------------------------------------------
__global__ __launch_bounds__(128) void head_k(const float* __restrict__ G,
                                              const float* __restrict__ l1w,
                                              const float* __restrict__ l1b,
                                              const float* __restrict__ l2w,
                                              const float* __restrict__ l2b,
                                              float* __restrict__ out) {
    int g = blockIdx.x;
    int j = threadIdx.x;
    __shared__ float gs[128];
    __shared__ float2 red[128];

    gs[j] = G[g * 128 + j];
    __syncthreads();

    float acc = l1b[j];
    for (int k = 0; k < 128; ++k) acc += gs[k] * l1w[k * 128 + j];
    float y = fmaxf(acc, 0.f);

    red[j] = make_float2(y * l2w[j * 2 + 0], y * l2w[j * 2 + 1]);
    __syncthreads();
    for (int s = 64; s > 0; s >>= 1) {
        if (j < s) {
            red[j].x += red[j + s].x;
            red[j].y += red[j + s].y;
        }
        __syncthreads();
    }
    if (j == 0) {
        float l0 = red[0].x + l2b[0];
        float l1 = red[0].y + l2b[1];
        float m = fmaxf(l0, l1);
        float lse = m + logf(expf(l0 - m) + expf(l1 - m));
        out[g * 2 + 0] = l0 - lse;
        out[g * 2 + 1] = l1 - lse;
    }
}

// ---------------------------------------------------------------------------
// Launch
// ---------------------------------------------------------------------------
extern "C" void kernel_launch(void* const* d_in, const int* in_sizes, int n_in,
                              void* d_out, int out_size, void* d_ws, size_t ws_size,
                              hipStream_t stream) {
    const float* x       = (const float*)d_in[0];
    const int*   ei      = (const int*)d_in[1];
    const int*   batch   = (const int*)d_in[2];
    const float* conv_w  = (const float*)d_in[3];
    const float* conv_b  = (const float*)d_in[4];
    const float* lin1_w  = (const float*)d_in[5];
    const float* lin1_b  = (const float*)d_in[6];
    const float* lin2_w  = (const float*)d_in[7];
    const float* lin2_b  = (const float*)d_in[8];
    float* out = (float*)d_out;

    const int n = in_sizes[0] / DIM;      // 100000
    const int E = in_sizes[1] / 2;        // 1600000
    const int n_graphs = 128;

    const int* src = ei;
    const int* dst = ei + E;

    // workspace layout (all 256B aligned)
    char* p = (char*)d_ws;
    auto alloc = [&](size_t bytes) {
        char* r = p;
        p += (bytes + 255) & ~(size_t)255;
        return r;
    };
    float* bufA   = (float*)alloc((size_t)n * DIM * 4);
    float* bufB   = (float*)alloc((size_t)n * DIM * 4);
    float* dis    = (float*)alloc((size_t)n * 4);
    int*   counts = (int*)alloc((size_t)n * 4);
    int*   incl   = (int*)alloc((size_t)n * 4);
    int*   rowptr = (int*)alloc((size_t)(n + 1) * 4);
    int*   cursor = (int*)alloc((size_t)n * 4);
    int*   bsum   = (int*)alloc(512 * 4);
    int*   col    = (int*)alloc((size_t)E * 4);
    float* wgt    = (float*)alloc((size_t)E * 4);
    float* gbuf   = (float*)alloc((size_t)n_graphs * DIM * 4);
    (void)ws_size;

    const int nScanBlocks = (n + 255) / 256;        // 391 (<=512)
    const int eBlocks = (E + 255) / 256;

    hipMemsetAsync(counts, 0, (size_t)n * 4, stream);
    hipMemsetAsync(gbuf, 0, (size_t)n_graphs * DIM * 4, stream);
    count_k<<<eBlocks, 256, 0, stream>>>(dst, counts, E);
    scan1_k<<<nScanBlocks, 256, 0, stream>>>(counts, incl, bsum, n);
    scan2_k<<<1, 512, 0, stream>>>(bsum, nScanBlocks);
    scan3_k<<<nScanBlocks, 256, 0, stream>>>(counts, incl, bsum, rowptr, cursor, dis, n, E);
    fill_k<<<eBlocks, 256, 0, stream>>>(src, dst, cursor, col, wgt, dis, E);

    const int gemmBlocks = (n + GR - 1) / GR;
    const int aggBlocks = (n + 3) / 4;

    // layer 0: x -> bufB -> bufA
    gemm_k<<<gemmBlocks, 256, 0, stream>>>(x, conv_w + 0 * DIM * DIM, bufB, n);
    agg_k<<<aggBlocks, 256, 0, stream>>>(bufB, rowptr, col, wgt, dis, conv_b + 0 * DIM, bufA, n);
    // layer 1
    gemm_k<<<gemmBlocks, 256, 0, stream>>>(bufA, conv_w + 1 * DIM * DIM, bufB, n);
    agg_k<<<aggBlocks, 256, 0, stream>>>(bufB, rowptr, col, wgt, dis, conv_b + 1 * DIM, bufA, n);
    // layer 2
    gemm_k<<<gemmBlocks, 256, 0, stream>>>(bufA, conv_w + 2 * DIM * DIM, bufB, n);
    agg_k<<<aggBlocks, 256, 0, stream>>>(bufB, rowptr, col, wgt, dis, conv_b + 2 * DIM, bufA, n);

    dim3 pgrid(n_graphs, POOL_SPLIT);
    pool_k<<<pgrid, 64, 0, stream>>>(bufA, batch, gbuf, n);
    head_k<<<n_graphs, 128, 0, stream>>>(gbuf, lin1_w, lin1_b, lin2_w, lin2_b, out);
}

// Round 5
// 637.655 us; speedup vs baseline: 2.7620x; 1.2688x over previous
//
#include <hip/hip_runtime.h>
#include <hip/hip_fp16.h>
#include <math.h>

#define DIM 128
#define GR 64          // rows per GEMM block
#define ALD 132        // A-tile LDS row stride (floats): %4==0 for b128, %32==4 -> conflict-free
#define POOL_SPLIT 32  // partial-sum blocks per graph

// ---------------------------------------------------------------------------
// Graph build kernels
// ---------------------------------------------------------------------------

__global__ void count_k(const int* __restrict__ dst, int* __restrict__ counts, int E) {
    int e = blockIdx.x * 256 + threadIdx.x;
    if (e < E) atomicAdd(&counts[dst[e]], 1);
}

// per-block inclusive scan of counts -> incl, block sums -> bsum
__global__ void scan1_k(const int* __restrict__ counts, int* __restrict__ incl,
                        int* __restrict__ bsum, int n) {
    __shared__ int s[256];
    int i = blockIdx.x * 256 + threadIdx.x;
    int v = (i < n) ? counts[i] : 0;
    s[threadIdx.x] = v;
    __syncthreads();
    for (int off = 1; off < 256; off <<= 1) {
        int t = (threadIdx.x >= (unsigned)off) ? s[threadIdx.x - off] : 0;
        __syncthreads();
        s[threadIdx.x] += t;
        __syncthreads();
    }
    if (i < n) incl[i] = s[threadIdx.x];
    if (threadIdx.x == 255) bsum[blockIdx.x] = s[255];
}

// single-block scan of block sums (nb <= 512), in-place -> exclusive
__global__ void scan2_k(int* __restrict__ bsum, int nb) {
    __shared__ int s[512];
    int v = (threadIdx.x < (unsigned)nb) ? bsum[threadIdx.x] : 0;
    s[threadIdx.x] = v;
    __syncthreads();
    for (int off = 1; off < 512; off <<= 1) {
        int t = (threadIdx.x >= (unsigned)off) ? s[threadIdx.x - off] : 0;
        __syncthreads();
        s[threadIdx.x] += t;
        __syncthreads();
    }
    bsum[threadIdx.x] = s[threadIdx.x] - v;  // exclusive
}

// finalize: rowptr (exclusive), cursor copy, dis = rsqrt(deg) with deg = counts+1 (self loop)
__global__ void scan3_k(const int* __restrict__ counts, const int* __restrict__ incl,
                        const int* __restrict__ bsum, int* __restrict__ rowptr,
                        int* __restrict__ cursor, float* __restrict__ dis, int n, int E) {
    int i = blockIdx.x * 256 + threadIdx.x;
    if (i < n) {
        int excl = incl[i] - counts[i] + bsum[blockIdx.x];
        rowptr[i] = excl;
        cursor[i] = excl;
        dis[i]    = rsqrtf((float)(counts[i] + 1));
    }
    if (i == 0) rowptr[n] = E;
}

// single 8B scatter per edge: {col, wgt} packed (one cache line touch, not two)
__global__ void fill_k(const int* __restrict__ src, const int* __restrict__ dst,
                       int* __restrict__ cursor, int2* __restrict__ ew,
                       const float* __restrict__ dis, int E) {
    int e = blockIdx.x * 256 + threadIdx.x;
    if (e < E) {
        int s = src[e], d = dst[e];
        int p = atomicAdd(&cursor[d], 1);
        ew[p] = make_int2(s, __float_as_int(dis[s] * dis[d]));
    }
}

// ---------------------------------------------------------------------------
// GEMM: T[n,128](fp16) = A[n,128](fp32) @ W[128,128]   (fp32 vector ALU,
// fp32 accumulate, fp16 output for the gather-heavy aggregation stage)
// ---------------------------------------------------------------------------
__global__ __launch_bounds__(256) void gemm_k(const float* __restrict__ A,
                                              const float* __restrict__ W,
                                              __half* __restrict__ T, int n) {
    __shared__ float Al[GR * ALD];
    const int r0 = blockIdx.x * GR;
    const int t  = threadIdx.x;
    const int tx = t & 31;
    const int ty = t >> 5;

    const int nrows = min(GR, n - r0);
    for (int idx = t; idx < GR * 32; idx += 256) {
        int row = idx >> 5, c4 = idx & 31;
        float4 v = make_float4(0.f, 0.f, 0.f, 0.f);
        if (row < nrows) v = ((const float4*)(A + (size_t)(r0 + row) * DIM))[c4];
        *(float4*)&Al[row * ALD + c4 * 4] = v;
    }
    __syncthreads();

    float acc[8][4];
#pragma unroll
    for (int i = 0; i < 8; ++i)
#pragma unroll
        for (int j = 0; j < 4; ++j) acc[i][j] = 0.f;

    const float4* Wg = (const float4*)W;
    for (int k = 0; k < DIM; k += 4) {
        float4 w0 = Wg[(k + 0) * 32 + tx];
        float4 w1 = Wg[(k + 1) * 32 + tx];
        float4 w2 = Wg[(k + 2) * 32 + tx];
        float4 w3 = Wg[(k + 3) * 32 + tx];
#pragma unroll
        for (int i = 0; i < 8; ++i) {
            const float4 a4 = *(const float4*)&Al[(ty + 8 * i) * ALD + k];
            acc[i][0] += a4.x * w0.x; acc[i][1] += a4.x * w0.y;
            acc[i][2] += a4.x * w0.z; acc[i][3] += a4.x * w0.w;
            acc[i][0] += a4.y * w1.x; acc[i][1] += a4.y * w1.y;
            acc[i][2] += a4.y * w1.z; acc[i][3] += a4.y * w1.w;
            acc[i][0] += a4.z * w2.x; acc[i][1] += a4.z * w2.y;
            acc[i][2] += a4.z * w2.z; acc[i][3] += a4.z * w2.w;
            acc[i][0] += a4.w * w3.x; acc[i][1] += a4.w * w3.y;
            acc[i][2] += a4.w * w3.z; acc[i][3] += a4.w * w3.w;
        }
    }

#pragma unroll
    for (int i = 0; i < 8; ++i) {
        int row = ty + 8 * i;
        if (row < nrows) {
            __half2 lo = __floats2half2_rn(acc[i][0], acc[i][1]);
            __half2 hi = __floats2half2_rn(acc[i][2], acc[i][3]);
            int2 pk = make_int2(*(int*)&lo, *(int*)&hi);
            ((int2*)(T + (size_t)(r0 + row) * DIM))[tx] = pk;  // 8B = 4 halves
        }
    }
}

// ---------------------------------------------------------------------------
// Aggregation: O[v] = relu( dis[v]^2 * T[v] + sum_e wgt[e]*T[col[e]] + b )
// one wave per node; lane handles 2 dims (one half2 = 4B -> 256B/row gather).
// fp32 accumulate. Edge loop unrolled 8/4 for memory-level parallelism.
// ---------------------------------------------------------------------------
__global__ __launch_bounds__(256) void agg_k(const __half* __restrict__ T,
                                             const int* __restrict__ rowptr,
                                             const int2* __restrict__ ew,
                                             const float* __restrict__ dis,
                                             const float* __restrict__ bias,
                                             float* __restrict__ O, int n) {
    int lane = threadIdx.x & 63;
    int v = blockIdx.x * 4 + (threadIdx.x >> 6);
    if (v >= n) return;

    const __half2* T2 = (const __half2*)T;  // 64 half2 per row
    float dv = dis[v];
    int e0 = rowptr[v], e1 = rowptr[v + 1];

    float2 t = __half22float2(T2[(size_t)v * 64 + lane]);
    float2 acc;
    acc.x = t.x * dv * dv;
    acc.y = t.y * dv * dv;

    int e = e0;
    for (; e + 8 <= e1; e += 8) {
        int2 p0 = ew[e + 0], p1 = ew[e + 1], p2 = ew[e + 2], p3 = ew[e + 3];
        int2 p4 = ew[e + 4], p5 = ew[e + 5], p6 = ew[e + 6], p7 = ew[e + 7];
        float2 u0 = __half22float2(T2[(size_t)p0.x * 64 + lane]);
        float2 u1 = __half22float2(T2[(size_t)p1.x * 64 + lane]);
        float2 u2 = __half22float2(T2[(size_t)p2.x * 64 + lane]);
        float2 u3 = __half22float2(T2[(size_t)p3.x * 64 + lane]);
        float2 u4 = __half22float2(T2[(size_t)p4.x * 64 + lane]);
        float2 u5 = __half22float2(T2[(size_t)p5.x * 64 + lane]);
        float2 u6 = __half22float2(T2[(size_t)p6.x * 64 + lane]);
        float2 u7 = __half22float2(T2[(size_t)p7.x * 64 + lane]);
        float w0 = __int_as_float(p0.y), w1 = __int_as_float(p1.y);
        float w2 = __int_as_float(p2.y), w3 = __int_as_float(p3.y);
        float w4 = __int_as_float(p4.y), w5 = __int_as_float(p5.y);
        float w6 = __int_as_float(p6.y), w7 = __int_as_float(p7.y);
        acc.x += w0 * u0.x; acc.y += w0 * u0.y;
        acc.x += w1 * u1.x; acc.y += w1 * u1.y;
        acc.x += w2 * u2.x; acc.y += w2 * u2.y;
        acc.x += w3 * u3.x; acc.y += w3 * u3.y;
        acc.x += w4 * u4.x; acc.y += w4 * u4.y;
        acc.x += w5 * u5.x; acc.y += w5 * u5.y;
        acc.x += w6 * u6.x; acc.y += w6 * u6.y;
        acc.x += w7 * u7.x; acc.y += w7 * u7.y;
    }
    for (; e + 4 <= e1; e += 4) {
        int2 p0 = ew[e + 0], p1 = ew[e + 1], p2 = ew[e + 2], p3 = ew[e + 3];
        float2 u0 = __half22float2(T2[(size_t)p0.x * 64 + lane]);
        float2 u1 = __half22float2(T2[(size_t)p1.x * 64 + lane]);
        float2 u2 = __half22float2(T2[(size_t)p2.x * 64 + lane]);
        float2 u3 = __half22float2(T2[(size_t)p3.x * 64 + lane]);
        float w0 = __int_as_float(p0.y), w1 = __int_as_float(p1.y);
        float w2 = __int_as_float(p2.y), w3 = __int_as_float(p3.y);
        acc.x += w0 * u0.x; acc.y += w0 * u0.y;
        acc.x += w1 * u1.x; acc.y += w1 * u1.y;
        acc.x += w2 * u2.x; acc.y += w2 * u2.y;
        acc.x += w3 * u3.x; acc.y += w3 * u3.y;
    }
    for (; e < e1; ++e) {
        int2 p = ew[e];
        float w = __int_as_float(p.y);
        float2 u = __half22float2(T2[(size_t)p.x * 64 + lane]);
        acc.x += w * u.x;
        acc.y += w * u.y;
    }

    float2 b = ((const float2*)bias)[lane];
    float2 o;
    o.x = fmaxf(acc.x + b.x, 0.f);
    o.y = fmaxf(acc.y + b.y, 0.f);
    ((float2*)O)[(size_t)v * 64 + lane] = o;
}

// ---------------------------------------------------------------------------
// Global mean pool, split-parallel: grid (n_graphs, POOL_SPLIT), block = 1 wave.
// ---------------------------------------------------------------------------
__global__ __launch_bounds__(64) void pool_k(const float* __restrict__ H,
                                             const int* __restrict__ batch,
                                             float* __restrict__ G, int n) {
    int g = blockIdx.x;
    int part = blockIdx.y;

    int lo = 0, hi = n;
    while (lo < hi) { int m = (lo + hi) >> 1; if (batch[m] < g) lo = m + 1; else hi = m; }
    int start = lo;
    lo = start; hi = n;
    while (lo < hi) { int m = (lo + hi) >> 1; if (batch[m] < g + 1) lo = m + 1; else hi = m; }
    int end = lo;
    int cnt = end - start;
    if (cnt <= 0) return;
    float inv = 1.0f / (float)cnt;

    int lane = threadIdx.x;
    const float2* H2 = (const float2*)H;
    float2 s = make_float2(0.f, 0.f);
    for (int v = start + part; v < end; v += POOL_SPLIT) {
        float2 h = H2[(size_t)v * 64 + lane];
        s.x += h.x; s.y += h.y;
    }
    atomicAdd(&G[g * DIM + 2 * lane + 0], s.x * inv);
    atomicAdd(&G[g * DIM + 2 * lane + 1], s.y * inv);
}

// ---------------------------------------------------------------------------
// Head: y = relu(g@lin1+b1); logits = y@lin2+b2; out = log_softmax(logits)
// one block (128 threads) per graph
// ---------------------------------------------------------------------------
__global__ __launch_bounds__(128) void head_k(const float* __restrict__ G,
                                              const float* __restrict__ l1w,
                                              const float* __restrict__ l1b,
                                              const float* __restrict__ l2w,
                                              const float* __restrict__ l2b,
                                              float* __restrict__ out) {
    int g = blockIdx.x;
    int j = threadIdx.x;
    __shared__ float gs[128];
    __shared__ float2 red[128];

    gs[j] = G[g * 128 + j];
    __syncthreads();

    float acc = l1b[j];
    for (int k = 0; k < 128; ++k) acc += gs[k] * l1w[k * 128 + j];
    float y = fmaxf(acc, 0.f);

    red[j] = make_float2(y * l2w[j * 2 + 0], y * l2w[j * 2 + 1]);
    __syncthreads();
    for (int s = 64; s > 0; s >>= 1) {
        if (j < s) {
            red[j].x += red[j + s].x;
            red[j].y += red[j + s].y;
        }
        __syncthreads();
    }
    if (j == 0) {
        float l0 = red[0].x + l2b[0];
        float l1 = red[0].y + l2b[1];
        float m = fmaxf(l0, l1);
        float lse = m + logf(expf(l0 - m) + expf(l1 - m));
        out[g * 2 + 0] = l0 - lse;
        out[g * 2 + 1] = l1 - lse;
    }
}

// ---------------------------------------------------------------------------
// Launch
// ---------------------------------------------------------------------------
extern "C" void kernel_launch(void* const* d_in, const int* in_sizes, int n_in,
                              void* d_out, int out_size, void* d_ws, size_t ws_size,
                              hipStream_t stream) {
    const float* x       = (const float*)d_in[0];
    const int*   ei      = (const int*)d_in[1];
    const int*   batch   = (const int*)d_in[2];
    const float* conv_w  = (const float*)d_in[3];
    const float* conv_b  = (const float*)d_in[4];
    const float* lin1_w  = (const float*)d_in[5];
    const float* lin1_b  = (const float*)d_in[6];
    const float* lin2_w  = (const float*)d_in[7];
    const float* lin2_b  = (const float*)d_in[8];
    float* out = (float*)d_out;

    const int n = in_sizes[0] / DIM;      // 100000
    const int E = in_sizes[1] / 2;        // 1600000
    const int n_graphs = 128;

    const int* src = ei;
    const int* dst = ei + E;

    // workspace layout (all 256B aligned)
    char* p = (char*)d_ws;
    auto alloc = [&](size_t bytes) {
        char* r = p;
        p += (bytes + 255) & ~(size_t)255;
        return r;
    };
    float*  bufH   = (float*)alloc((size_t)n * DIM * 4);   // agg output (fp32)
    __half* bufT   = (__half*)alloc((size_t)n * DIM * 2);  // gemm output (fp16)
    float*  dis    = (float*)alloc((size_t)n * 4);
    int*    counts = (int*)alloc((size_t)n * 4);
    int*    incl   = (int*)alloc((size_t)n * 4);
    int*    rowptr = (int*)alloc((size_t)(n + 1) * 4);
    int*    cursor = (int*)alloc((size_t)n * 4);
    int*    bsum   = (int*)alloc(512 * 4);
    int2*   ew     = (int2*)alloc((size_t)E * 8);          // packed {col, wgt}
    float*  gbuf   = (float*)alloc((size_t)n_graphs * DIM * 4);
    (void)ws_size;

    const int nScanBlocks = (n + 255) / 256;        // 391 (<=512)
    const int eBlocks = (E + 255) / 256;

    hipMemsetAsync(counts, 0, (size_t)n * 4, stream);
    hipMemsetAsync(gbuf, 0, (size_t)n_graphs * DIM * 4, stream);
    count_k<<<eBlocks, 256, 0, stream>>>(dst, counts, E);
    scan1_k<<<nScanBlocks, 256, 0, stream>>>(counts, incl, bsum, n);
    scan2_k<<<1, 512, 0, stream>>>(bsum, nScanBlocks);
    scan3_k<<<nScanBlocks, 256, 0, stream>>>(counts, incl, bsum, rowptr, cursor, dis, n, E);
    fill_k<<<eBlocks, 256, 0, stream>>>(src, dst, cursor, ew, dis, E);

    const int gemmBlocks = (n + GR - 1) / GR;
    const int aggBlocks = (n + 3) / 4;

    // layer 0: x -> bufT -> bufH
    gemm_k<<<gemmBlocks, 256, 0, stream>>>(x, conv_w + 0 * DIM * DIM, bufT, n);
    agg_k<<<aggBlocks, 256, 0, stream>>>(bufT, rowptr, ew, dis, conv_b + 0 * DIM, bufH, n);
    // layer 1
    gemm_k<<<gemmBlocks, 256, 0, stream>>>(bufH, conv_w + 1 * DIM * DIM, bufT, n);
    agg_k<<<aggBlocks, 256, 0, stream>>>(bufT, rowptr, ew, dis, conv_b + 1 * DIM, bufH, n);
    // layer 2
    gemm_k<<<gemmBlocks, 256, 0, stream>>>(bufH, conv_w + 2 * DIM * DIM, bufT, n);
    agg_k<<<aggBlocks, 256, 0, stream>>>(bufT, rowptr, ew, dis, conv_b + 2 * DIM, bufH, n);

    dim3 pgrid(n_graphs, POOL_SPLIT);
    pool_k<<<pgrid, 64, 0, stream>>>(bufH, batch, gbuf, n);
    head_k<<<n_graphs, 128, 0, stream>>>(gbuf, lin1_w, lin1_b, lin2_w, lin2_b, out);
}